// Round 1
// baseline (184.517 us; speedup 1.0000x reference)
//
#include <hip/hip_runtime.h>

// HydrophobicPairs: E[b,l] = h[seq[b,l]] * sum_k h[seq[b, j_idx[b,l,k]]] * g(r[b,l,k])
// g(r) = exp(-(min(r,md)-r_peak)^2 / (2 sigma^2)) * (r < md - 1e-4)
// B=32, L=8192, K=64, NUM_AA=20.

#define BB 32
#define LL 8192
#define KK 64

__global__ __launch_bounds__(256) void _HydrophobicPairs_58256936403302_kernel(
    const int*   __restrict__ seq,        // [B,L]
    const float* __restrict__ r,          // [B,L,K]
    const int*   __restrict__ j_idx,      // [B,L,K]
    const float* __restrict__ h,          // [20]
    const float* __restrict__ r_half_raw, // [1]
    const float* __restrict__ tau_hp_raw, // [1]
    const int*   __restrict__ max_dist,   // [1]
    float*       __restrict__ out)        // [B,L]
{
    __shared__ float lds_h[20];
    const int tid = threadIdx.x;
    if (tid < 20) lds_h[tid] = h[tid];
    __syncthreads();

    // Runtime scalar params (broadcast loads, L2-cached).
    const float md     = (float)max_dist[0];
    const float r_peak = log1pf(expf(r_half_raw[0]));      // softplus
    const float sigma  = log1pf(expf(tau_hp_raw[0])) + 0.1f;
    const float inv2s2 = 1.0f / (2.0f * sigma * sigma);
    const float vthr   = md - 1e-4f;

    // 16 lanes per (b,l) row; block of 256 covers 16 consecutive rows.
    const int row  = blockIdx.x * 16 + (tid >> 4);   // global row = b*L + l
    const int lane = tid & 15;
    const int* seq_b = seq + (row & ~(LL - 1));      // seq + b*L  (L = 8192, pow2)

    const long base = (long)row * KK + lane * 4;
    const float4 r4 = *(const float4*)(r + base);    // 16B/lane, wave reads 1KB coalesced
    const int4   j4 = *(const int4*)(j_idx + base);

    float acc = 0.0f;
    #pragma unroll
    for (int t = 0; t < 4; ++t) {
        const float rv = (&r4.x)[t];
        int j = (&j4.x)[t];
        j = min(max(j, 0), LL - 1);
        const float hj = lds_h[seq_b[j]];            // global gather (L1) + LDS lookup
        const float rc = fminf(rv, md);
        const float d  = rc - r_peak;
        float g = __expf(-d * d * inv2s2);
        g = (rv < vthr) ? g : 0.0f;
        acc = fmaf(hj, g, acc);
    }

    // Butterfly reduce within each 16-lane group (wave64: masks 1,2,4,8 stay in-group).
    acc += __shfl_xor(acc, 1);
    acc += __shfl_xor(acc, 2);
    acc += __shfl_xor(acc, 4);
    acc += __shfl_xor(acc, 8);

    if (lane == 0) {
        const float hi = lds_h[seq[row]];
        out[row] = hi * acc;
    }
}

extern "C" void kernel_launch(void* const* d_in, const int* in_sizes, int n_in,
                              void* d_out, int out_size, void* d_ws, size_t ws_size,
                              hipStream_t stream) {
    const int*   seq        = (const int*)d_in[0];
    const float* r          = (const float*)d_in[1];
    const int*   j_idx      = (const int*)d_in[2];
    const float* h          = (const float*)d_in[3];
    const float* r_half_raw = (const float*)d_in[4];
    const float* tau_hp_raw = (const float*)d_in[5];
    const int*   max_dist   = (const int*)d_in[6];
    float*       out        = (float*)d_out;

    const int rows = BB * LL;              // 262144
    dim3 grid(rows / 16), block(256);      // 16 rows/block, 16 lanes/row
    _HydrophobicPairs_58256936403302_kernel<<<grid, block, 0, stream>>>(
        seq, r, j_idx, h, r_half_raw, tau_hp_raw, max_dist, out);
}

// Round 2
// 160.611 us; speedup vs baseline: 1.1488x; 1.1488x over previous
//
#include <hip/hip_runtime.h>

// HydrophobicPairs: E[b,l] = h[seq[b,l]] * sum_k h[seq[b, j_idx[b,l,k]]] * g(r[b,l,k])
// g(r) = exp(-(min(r,md)-r_peak)^2 / (2 sigma^2)) * (r < md - 1e-4)
// B=32, L=8192, K=64, NUM_AA=20.
//
// R1 design: per-block LDS staging of h_row[l] = h[seq[b,l]] (32 KB) turns the
// random gather into ds_read_b32 (L1/TA gather was the R0 bottleneck: 52% VALU,
// 12% HBM, 71 us). 512 rows/block amortizes staging to 25% of main elements.

#define BB 32
#define LL 8192
#define KK 64
#define TPB 1024
#define ROWS_PER_BLOCK 512   // 2 outer iters x 256 rows (4 lanes/row)

__global__ __launch_bounds__(TPB) void _HydrophobicPairs_58256936403302_kernel(
    const int*   __restrict__ seq,        // [B,L]
    const float* __restrict__ r,          // [B,L,K]
    const int*   __restrict__ j_idx,      // [B,L,K]
    const float* __restrict__ h,          // [20]
    const float* __restrict__ r_half_raw, // [1]
    const float* __restrict__ tau_hp_raw, // [1]
    const int*   __restrict__ max_dist,   // [1]
    float*       __restrict__ out)        // [B,L]
{
    __shared__ float h_row[LL];           // 32 KB: h[seq[b, 0..L)]
    __shared__ float h_tab[32];

    const int tid = threadIdx.x;
    if (tid < 20) h_tab[tid] = h[tid];
    __syncthreads();

    const int chunk = blockIdx.x & 15;    // 16 chunks of 512 rows per b
    const int b     = blockIdx.x >> 4;
    const int lbase = chunk * ROWS_PER_BLOCK;

    // Stage h[seq[b, :]] for the WHOLE b-row (j can reference any l).
    const int4* seq4 = (const int4*)(seq + b * LL);
    #pragma unroll
    for (int i = 0; i < 2; ++i) {
        const int idx = tid + i * TPB;    // 0..2047, int4 granularity
        const int4 s = seq4[idx];
        const float4 hv = make_float4(h_tab[s.x], h_tab[s.y], h_tab[s.z], h_tab[s.w]);
        ((float4*)h_row)[idx] = hv;
    }

    // Runtime scalars (broadcast, cached).
    const float md     = (float)max_dist[0];
    const float r_peak = log1pf(expf(r_half_raw[0]));       // softplus
    const float sigma  = log1pf(expf(tau_hp_raw[0])) + 0.1f;
    const float nscale = -1.44269504f / (2.0f * sigma * sigma);  // fold log2(e) into exp2
    const float vthr   = md - 1e-4f;

    __syncthreads();

    const int lane = tid & 3;             // 4 lanes per row, 16 elems/lane
    #pragma unroll
    for (int o = 0; o < 2; ++o) {
        const int l_loc = lbase + o * 256 + (tid >> 2);
        const int row   = b * LL + l_loc;
        const long base = (long)row * KK + lane * 16;

        // Preload all 64 B/lane up front (wave inst covers 4 KB contiguous).
        float4 r4[4]; int4 j4[4];
        #pragma unroll
        for (int t = 0; t < 4; ++t) {
            r4[t] = *(const float4*)(r + base + t * 4);
            j4[t] = *(const int4*)(j_idx + base + t * 4);
        }

        float acc = 0.0f;
        #pragma unroll
        for (int t = 0; t < 4; ++t) {
            #pragma unroll
            for (int u = 0; u < 4; ++u) {
                const float rv = (&r4[t].x)[u];
                const unsigned j = (unsigned)(&j4[t].x)[u] & (LL - 1);
                const float hj = h_row[j];                 // LDS gather
                const float d  = fminf(rv, md) - r_peak;
                float g = exp2f(d * d * nscale);           // v_exp_f32
                g = (rv < vthr) ? g : 0.0f;
                acc = fmaf(hj, g, acc);
            }
        }

        // Reduce across the 4-lane group.
        acc += __shfl_xor(acc, 1);
        acc += __shfl_xor(acc, 2);
        if (lane == 0) out[row] = h_row[l_loc] * acc;
    }
}

extern "C" void kernel_launch(void* const* d_in, const int* in_sizes, int n_in,
                              void* d_out, int out_size, void* d_ws, size_t ws_size,
                              hipStream_t stream) {
    const int*   seq        = (const int*)d_in[0];
    const float* r          = (const float*)d_in[1];
    const int*   j_idx      = (const int*)d_in[2];
    const float* h          = (const float*)d_in[3];
    const float* r_half_raw = (const float*)d_in[4];
    const float* tau_hp_raw = (const float*)d_in[5];
    const int*   max_dist   = (const int*)d_in[6];
    float*       out        = (float*)d_out;

    dim3 grid(BB * (LL / ROWS_PER_BLOCK)), block(TPB);   // 512 blocks x 1024 thr
    _HydrophobicPairs_58256936403302_kernel<<<grid, block, 0, stream>>>(
        seq, r, j_idx, h, r_half_raw, tau_hp_raw, max_dist, out);
}